// Round 3
// baseline (191.732 us; speedup 1.0000x reference)
//
#include <hip/hip_runtime.h>
#include <hip/hip_bf16.h>
#include <math.h>

#define E_N 50
#define D_N 100
#define H_N 100
#define XS_LD 102   // halfwords per xs row: odd word stride -> conflict-free

__device__ __forceinline__ float bf2f(unsigned int s16) {
    return __uint_as_float(s16 << 16);
}

__device__ __forceinline__ unsigned short f2bf(float f) {
    unsigned int u = __float_as_uint(f);
    unsigned int r = (u + 0x7FFFu + ((u >> 16) & 1u)) >> 16;  // RNE
    return (unsigned short)r;
}

template <bool F32>
__device__ __forceinline__ float ldx(const void* p, int i) {
    if (F32) return reinterpret_cast<const float*>(p)[i];
    return bf2f(reinterpret_cast<const unsigned short*>(p)[i]);
}

template <bool F32>
__device__ __forceinline__ float4 ld4(const void* p, long long i4) {
    if (F32) return reinterpret_cast<const float4*>(p)[i4];
    uint2 v = reinterpret_cast<const uint2*>(p)[i4];
    float4 f;
    f.x = bf2f(v.x & 0xFFFFu);
    f.y = bf2f(v.x >> 16);
    f.z = bf2f(v.y & 0xFFFFu);
    f.w = bf2f(v.y >> 16);
    return f;
}

// detector: even halfwords of emb decode sane iff data is bf16
__device__ __forceinline__ int detect_f32(const void* emb, int tid, int* flag_s) {
    if (tid < 64) {
        unsigned short hw = reinterpret_cast<const unsigned short*>(emb)[tid * 2];
        float v = bf2f(hw);
        float a = fabsf(v);
        int sane = (v == 0.f) || (a >= 1e-4f && a <= 8.0f);
        unsigned long long ball = __ballot(sane);
        if (tid == 0) *flag_s = (__popcll(ball) < 32) ? 1 : 0;
    }
    __syncthreads();
    return *flag_s;
}

// ---------------- K1: Mt[e*100+d] = sum_h Wk[d,h]*Wq[e,h];  c = Wk*bq;  b2 = bs+bv ----
template <bool F32>
__device__ __forceinline__ void prep_core(const void* Wq, const void* bq,
                                          const void* Wk, const void* bv,
                                          const void* bs,
                                          float* Mt, float* c, float* b2,
                                          int blk, int t) {
    if (blk < D_N) {           // e = blk
        if (t < D_N) {
            float acc = 0.f;
            #pragma unroll 10
            for (int h = 0; h < H_N; ++h)
                acc = fmaf(ldx<F32>(Wk, t * H_N + h), ldx<F32>(Wq, blk * H_N + h), acc);
            Mt[blk * D_N + t] = acc;
        }
    } else {                   // c and b2
        if (t < D_N) {
            float acc = 0.f;
            #pragma unroll 10
            for (int h = 0; h < H_N; ++h)
                acc = fmaf(ldx<F32>(Wk, t * H_N + h), ldx<F32>(bq, h), acc);
            c[t] = acc;
            b2[t] = ldx<F32>(bs, t) + ldx<F32>(bv, t);
        }
    }
}

__global__ __launch_bounds__(128)
void prep_kernel(const void* __restrict__ emb,
                 const void* __restrict__ Wq, const void* __restrict__ bq,
                 const void* __restrict__ Wk, const void* __restrict__ bv,
                 const void* __restrict__ bs,
                 float* __restrict__ Mt, float* __restrict__ c,
                 float* __restrict__ b2) {
    __shared__ int flag_s;
    int t = threadIdx.x;
    int f32 = detect_f32(emb, t, &flag_s);
    if (f32) prep_core<true>(Wq, bq, Wk, bv, bs, Mt, c, b2, blockIdx.x, t);
    else     prep_core<false>(Wq, bq, Wk, bv, bs, Mt, c, b2, blockIdx.x, t);
}

// ---------------- K2: main per-graph kernel, 2 graphs / 256-thread block ----------
template <bool F32>
__device__ __forceinline__ void graph_core(
    int g, int sub, int t,
    const int* __restrict__ nbr, const int* __restrict__ adj,
    const void* __restrict__ emb,
    const void* __restrict__ Wv, const void* __restrict__ Ws,
    const void* __restrict__ bv,
    const float* __restrict__ Mt, const float* __restrict__ c,
    const float* __restrict__ b2, void* __restrict__ out,
    unsigned short (*xs)[E_N * XS_LD], float (*x0s)[D_N],
    int (*ids)[E_N], int (*msk)[E_N], float (*us)[D_N],
    float (*ssc)[E_N], float (*attns)[E_N], float (*ys)[D_N], float* den_s)
{
    // ---- phase 1: ids/msk (lanes 0-49) + x0 gather (lanes 64-88, f32) ----
    if (t < E_N) {
        ids[sub][t] = nbr[g * E_N + t];
        msk[sub][t] = adj[(size_t)g * (E_N * E_N) + t * E_N];  // adj[g, j, 0]
    } else if (t >= 64 && t < 64 + 25) {
        int id0 = nbr[g * E_N];
        int q = t - 64;
        float4 f = ld4<F32>(emb, (long long)id0 * (D_N / 4) + q);
        x0s[sub][4 * q + 0] = f.x;
        x0s[sub][4 * q + 1] = f.y;
        x0s[sub][4 * q + 2] = f.z;
        x0s[sub][4 * q + 3] = f.w;
    }
    __syncthreads();

    // ---- phase 2: gather all rows -> xs (bf16-packed, padded rows) ----
    {
        unsigned int* xw = reinterpret_cast<unsigned int*>(xs[sub]);
        for (int i = t; i < E_N * (D_N / 4); i += 128) {  // 1250 quads
            int j = i / 25;
            int q = i - j * 25;
            float4 f = ld4<F32>(emb, (long long)ids[sub][j] * (D_N / 4) + q);
            unsigned int w0 = (unsigned int)f2bf(f.x) | ((unsigned int)f2bf(f.y) << 16);
            unsigned int w1 = (unsigned int)f2bf(f.z) | ((unsigned int)f2bf(f.w) << 16);
            int wbase = j * (XS_LD / 2) + 2 * q;  // halfword base j*102+4q, even
            xw[wbase] = w0;
            xw[wbase + 1] = w1;
        }
    }
    __syncthreads();

    // ---- phase 3: u[d] = c[d] + sum_e Mt[e,d] * x0[e] ----
    if (t < D_N) {
        float acc = c[t];
        #pragma unroll 10
        for (int e = 0; e < D_N; ++e)
            acc = fmaf(Mt[e * D_N + t], x0s[sub][e], acc);
        us[sub][t] = acc;
    }
    __syncthreads();

    // ---- phase 4: scores s_j = 0.1 * (u . x_j) ----
    if (t < E_N) {
        const unsigned int* xw = reinterpret_cast<const unsigned int*>(xs[sub])
                                 + t * (XS_LD / 2);
        float acc = 0.f;
        #pragma unroll 10
        for (int d2 = 0; d2 < D_N / 2; ++d2) {
            unsigned int w = xw[d2];
            acc = fmaf(bf2f(w & 0xFFFFu), us[sub][2 * d2], acc);
            acc = fmaf(bf2f(w >> 16),     us[sub][2 * d2 + 1], acc);
        }
        ssc[sub][t] = acc * 0.1f;
    }
    __syncthreads();

    // ---- phase 5: masked softmax numerators ----
    if (t < E_N) {
        float m = -3.0e38f;
        #pragma unroll 10
        for (int j = 0; j < E_N; ++j)
            if (msk[sub][j]) m = fmaxf(m, ssc[sub][j]);
        attns[sub][t] = msk[sub][t] ? __expf(ssc[sub][t] - m) : 0.f;
    }
    __syncthreads();

    // ---- phase 6: y[d] = (sum_j e_j x[j,d]) / den ----
    if (t < D_N) {
        float den = 0.f;
        #pragma unroll 10
        for (int j = 0; j < E_N; ++j) den += attns[sub][j];
        float inv = den > 0.f ? 1.0f / den : 0.f;
        float acc = 0.f;
        #pragma unroll 10
        for (int j = 0; j < E_N; ++j) {
            float xv = bf2f(xs[sub][j * XS_LD + t]);
            acc = fmaf(attns[sub][j], xv, acc);
        }
        ys[sub][t] = acc * inv;
        if (t == 0) den_s[sub] = den;
    }
    __syncthreads();

    // ---- phase 7: out[h] = b2[h] (- bv if no edges) + y.Wv[:,h] + x0.Ws[:,h] ----
    if (t < H_N) {
        float acc = b2[t];
        if (!(den_s[sub] > 0.f)) acc -= ldx<F32>(bv, t);  // never in practice
        #pragma unroll 10
        for (int d = 0; d < D_N; ++d) {
            acc = fmaf(ys[sub][d],  ldx<F32>(Wv, d * H_N + t), acc);
            acc = fmaf(x0s[sub][d], ldx<F32>(Ws, d * H_N + t), acc);
        }
        size_t o = (size_t)g * H_N + t;
        if (F32) reinterpret_cast<float*>(out)[o] = acc;
        else     reinterpret_cast<unsigned short*>(out)[o] = f2bf(acc);
    }
}

__global__ __launch_bounds__(256)
void graph_enc_kernel(const int* __restrict__ nbr,
                      const int* __restrict__ adj,
                      const void* __restrict__ emb,
                      const void* __restrict__ Wv, const void* __restrict__ Ws,
                      const void* __restrict__ bv,
                      const float* __restrict__ Mt, const float* __restrict__ c,
                      const float* __restrict__ b2,
                      void* __restrict__ out, int G)
{
    __shared__ unsigned short xs[2][E_N * XS_LD];
    __shared__ float x0s[2][D_N];
    __shared__ int   ids[2][E_N];
    __shared__ int   msk[2][E_N];
    __shared__ float us[2][D_N];
    __shared__ float ssc[2][E_N];
    __shared__ float attns[2][E_N];
    __shared__ float ys[2][D_N];
    __shared__ float den_s[2];
    __shared__ int   flag_s;

    const int tid = threadIdx.x;
    const int sub = tid >> 7;
    const int t   = tid & 127;
    const int g   = blockIdx.x * 2 + sub;

    int f32 = detect_f32(emb, tid, &flag_s);
    if (g >= G) {  // still must hit the same barriers as working threads
        for (int i = 0; i < 6; ++i) __syncthreads();
        return;
    }
    if (f32)
        graph_core<true>(g, sub, t, nbr, adj, emb, Wv, Ws, bv, Mt, c, b2, out,
                         xs, x0s, ids, msk, us, ssc, attns, ys, den_s);
    else
        graph_core<false>(g, sub, t, nbr, adj, emb, Wv, Ws, bv, Mt, c, b2, out,
                          xs, x0s, ids, msk, us, ssc, attns, ys, den_s);
}

extern "C" void kernel_launch(void* const* d_in, const int* in_sizes, int n_in,
                              void* d_out, int out_size, void* d_ws, size_t ws_size,
                              hipStream_t stream) {
    const int* nbr = (const int*)d_in[0];
    const int* adj = (const int*)d_in[1];
    const void* emb = d_in[2];
    const void* Wq  = d_in[3];
    const void* bq  = d_in[4];
    const void* Wk  = d_in[5];
    // d_in[6] = bk: cancels inside softmax — unused
    const void* Wv  = d_in[7];
    const void* bv  = d_in[8];
    const void* Ws  = d_in[9];
    const void* bs  = d_in[10];

    float* Mt = (float*)d_ws;            // 100*100 f32
    float* c  = Mt + D_N * D_N;          // 100 f32
    float* b2 = c + D_N;                 // 100 f32

    const int G = in_sizes[0] / E_N;     // B*L = 3200

    prep_kernel<<<D_N + 1, 128, 0, stream>>>(emb, Wq, bq, Wk, bv, bs, Mt, c, b2);
    graph_enc_kernel<<<(G + 1) / 2, 256, 0, stream>>>(
        nbr, adj, emb, Wv, Ws, bv, Mt, c, b2, d_out, G);
}